// Round 1
// baseline (1053.250 us; speedup 1.0000x reference)
//
#include <hip/hip_runtime.h>
#include <stdint.h>

#define N_TASK 50000
#define N_RET 20000
#define N_DRAM 5000
#define N_LINK 100000
#define E_RET 1000000
#define E_DRAM 250000
#define E_LINK 2000000
#define HF 64

// ---- order-preserving float<->uint transform (for atomic min/max on float) ----
// ford(f) is strictly monotone; ford never produces 0x00000000 (needs NaN 0xFFFFFFFF)
// and never 0xFFFFFFFF (needs NaN 0x7FFFFFFF). So memset(0)/memset(0xFF) are safe
// "empty" sentinels for max/min respectively.
__device__ __forceinline__ unsigned ford(float f) {
  unsigned u = __float_as_uint(f);
  return (u & 0x80000000u) ? ~u : (u | 0x80000000u);
}
__device__ __forceinline__ float funord(unsigned t) {
  unsigned u = (t & 0x80000000u) ? (t & 0x7fffffffu) : ~t;
  return __uint_as_float(u);
}

// ---- K1: scalar segment sums per module + link degree counts ----
__global__ void k_segsum(const float* __restrict__ fr, const float* __restrict__ fd,
                         const float* __restrict__ fl,
                         const int* __restrict__ mr, const int* __restrict__ md,
                         const int* __restrict__ ml,
                         float* s_ret, float* s_dram, float* s_link, int* cnt) {
  int i = blockIdx.x * blockDim.x + threadIdx.x;
  const int total = E_RET + E_DRAM + E_LINK;
  if (i >= total) return;
  if (i < E_RET) {
    atomicAdd(&s_ret[mr[i]], fr[i]);
  } else if (i < E_RET + E_DRAM) {
    int j = i - E_RET;
    atomicAdd(&s_dram[md[j]], fd[j]);
  } else {
    int j = i - (E_RET + E_DRAM);
    int m = ml[j];
    atomicAdd(&s_link[m], fl[j]);
    atomicAdd(&cnt[m], 1);
  }
}

// ---- K2: per-task scalar min/max of module sums (ordered-uint atomics) ----
__global__ void k_minmax(const float* __restrict__ s_ret, const float* __restrict__ s_dram,
                         const float* __restrict__ s_link,
                         const int* __restrict__ tr, const int* __restrict__ mr,
                         const int* __restrict__ td, const int* __restrict__ md,
                         const int* __restrict__ tl, const int* __restrict__ ml,
                         unsigned* tmax, unsigned* tmin) {
  int i = blockIdx.x * blockDim.x + threadIdx.x;
  const int total = E_RET + E_DRAM + E_LINK;
  if (i >= total) return;
  int e, task; unsigned u;
  if (i < E_RET) {
    u = ford(s_ret[mr[i]]); task = tr[i]; e = 0;
  } else if (i < E_RET + E_DRAM) {
    int j = i - E_RET;
    u = ford(s_dram[md[j]]); task = td[j]; e = 1;
  } else {
    int j = i - (E_RET + E_DRAM);
    u = ford(s_link[ml[j]]); task = tl[j]; e = 2;
  }
  atomicMax(&tmax[e * N_TASK + task], u);
  atomicMin(&tmin[e * N_TASK + task], u);
}

// ---- scan chain for CSR offsets over cnt[N_LINK] ----
__global__ void k_part(const int* __restrict__ cnt, int* part) {
  __shared__ int sm[256];
  int i = blockIdx.x * 256 + threadIdx.x;
  sm[threadIdx.x] = (i < N_LINK) ? cnt[i] : 0;
  __syncthreads();
  for (int s = 128; s > 0; s >>= 1) {
    if (threadIdx.x < s) sm[threadIdx.x] += sm[threadIdx.x + s];
    __syncthreads();
  }
  if (threadIdx.x == 0) part[blockIdx.x] = sm[0];
}

__global__ void k_scanpart(const int* __restrict__ part, int* partx, int npart) {
  __shared__ int sm[512];
  int t = threadIdx.x;
  int v = (t < npart) ? part[t] : 0;
  sm[t] = v;
  __syncthreads();
  for (int d = 1; d < 512; d <<= 1) {
    int x = (t >= d) ? sm[t - d] : 0;
    __syncthreads();
    sm[t] += x;
    __syncthreads();
  }
  if (t < npart) partx[t] = sm[t] - v;  // exclusive
}

__global__ void k_offs(const int* __restrict__ cnt, const int* __restrict__ partx,
                       int* offs, int* cursor) {
  __shared__ int sm[256];
  int i = blockIdx.x * 256 + threadIdx.x;
  int t = threadIdx.x;
  int v = (i < N_LINK) ? cnt[i] : 0;
  sm[t] = v;
  __syncthreads();
  for (int d = 1; d < 256; d <<= 1) {
    int x = (t >= d) ? sm[t - d] : 0;
    __syncthreads();
    sm[t] += x;
    __syncthreads();
  }
  if (i < N_LINK) {
    int o = partx[blockIdx.x] + sm[t] - v;  // exclusive start
    offs[i] = o;
    cursor[i] = o;
  }
}

__global__ void k_scatter(const int* __restrict__ tl, const int* __restrict__ ml,
                          int* cursor, int* csr) {
  int i = blockIdx.x * blockDim.x + threadIdx.x;
  if (i >= E_LINK) return;
  int pos = atomicAdd(&cursor[ml[i]], 1);
  csr[pos] = tl[i];
}

// ---- K3: h_task = tanh(h_cat @ W_task^T + b_task), h_cat built on the fly ----
// 1 wave/block, 64 tasks x 64 outs tile, 8x8 register tile per thread.
// k runs over 3 chunks of 64 (chunk == etype).
__global__ __launch_bounds__(64) void k_task(
    const float* __restrict__ W_ret, const float* __restrict__ b_ret,
    const float* __restrict__ W_dram, const float* __restrict__ b_dram,
    const float* __restrict__ W_link, const float* __restrict__ b_link,
    const float* __restrict__ W_task, const float* __restrict__ b_task,
    const unsigned* __restrict__ tmax, const unsigned* __restrict__ tmin,
    unsigned short* __restrict__ h_task) {
  __shared__ __attribute__((aligned(16))) float hcS[64 * 64];  // [task_local][k]
  __shared__ __attribute__((aligned(16))) float wtS[64 * 64];  // [k][o]
  int tid = threadIdx.x;
  int tx = tid & 7, ty = tid >> 3;
  int o0 = tx * 8;
  int tile0 = blockIdx.x * 64;

  float acc[8][8];
#pragma unroll
  for (int i = 0; i < 8; i++)
#pragma unroll
    for (int j = 0; j < 8; j++) acc[i][j] = 0.f;

  const float* We[3] = {W_ret, W_dram, W_link};
  const float* be[3] = {b_ret, b_dram, b_link};

  for (int e = 0; e < 3; e++) {
    // stage W_task chunk transposed: wtS[k*64+o] = W_task[o*192 + e*64 + k]
    for (int idx = tid; idx < 4096; idx += 64) {
      int k = idx >> 6, o = idx & 63;
      wtS[idx] = W_task[o * 192 + e * 64 + k];
    }
    // build h_cat chunk: hcS[tl*64+k]
    for (int idx = tid; idx < 4096; idx += 64) {
      int tl = idx >> 6, k = idx & 63;
      int t = tile0 + tl;
      float hc = 0.f;
      if (t < N_TASK) {
        unsigned um = tmax[e * N_TASK + t];
        if (um != 0u) {  // deg>0
          float smax = funord(um);
          float smin = funord(tmin[e * N_TASK + t]);
          float w = We[e][k];
          float ssel = (w >= 0.f) ? smax : smin;  // monotone tanh: pick extreme s
          hc = tanhf(fmaf(ssel, w, be[e][k]));
        }
      }
      hcS[idx] = hc;
    }
    __syncthreads();
#pragma unroll
    for (int k4 = 0; k4 < 16; k4++) {
      int k = k4 * 4;
      float4 hv[8];
#pragma unroll
      for (int i = 0; i < 8; i++) hv[i] = *(const float4*)&hcS[(ty * 8 + i) * 64 + k];
      float wv[4][8];
#pragma unroll
      for (int dk = 0; dk < 4; dk++) {
        float4 a = *(const float4*)&wtS[(k + dk) * 64 + o0];
        float4 b = *(const float4*)&wtS[(k + dk) * 64 + o0 + 4];
        wv[dk][0] = a.x; wv[dk][1] = a.y; wv[dk][2] = a.z; wv[dk][3] = a.w;
        wv[dk][4] = b.x; wv[dk][5] = b.y; wv[dk][6] = b.z; wv[dk][7] = b.w;
      }
#pragma unroll
      for (int i = 0; i < 8; i++) {
        float hvv[4] = {hv[i].x, hv[i].y, hv[i].z, hv[i].w};
#pragma unroll
        for (int dk = 0; dk < 4; dk++)
#pragma unroll
          for (int j = 0; j < 8; j++)
            acc[i][j] = fmaf(hvv[dk], wv[dk][j], acc[i][j]);
      }
    }
    __syncthreads();
  }

  // epilogue: tanh(acc + b_task), store bf16 (RNE)
#pragma unroll
  for (int i = 0; i < 8; i++) {
    int t = tile0 + ty * 8 + i;
    if (t < N_TASK) {
#pragma unroll
      for (int g = 0; g < 2; g++) {
        ushort4 r;
        unsigned short rr[4];
#pragma unroll
        for (int j = 0; j < 4; j++) {
          float v = tanhf(acc[i][g * 4 + j] + b_task[o0 + g * 4 + j]);
          unsigned u = __float_as_uint(v);
          rr[j] = (unsigned short)((u + 0x7fffu + ((u >> 16) & 1u)) >> 16);
        }
        r.x = rr[0]; r.y = rr[1]; r.z = rr[2]; r.w = rr[3];
        *(ushort4*)&h_task[t * 64 + o0 + g * 4] = r;
      }
    }
  }
}

// ---- K4: per-link mean of h_task rows via CSR; wave per link, lane = feature ----
__global__ __launch_bounds__(256) void k_link(const unsigned short* __restrict__ h_task,
                                              const int* __restrict__ offs,
                                              const int* __restrict__ cnt,
                                              const int* __restrict__ csr,
                                              float* __restrict__ out) {
  int wid = threadIdx.x >> 6, lane = threadIdx.x & 63;
  int l = blockIdx.x * 4 + wid;  // grid exact: 25000*4 == N_LINK
  int start = offs[l];
  int c = cnt[l];
  float acc = 0.f;
  for (int q = 0; q < c; q++) {
    int task = csr[start + q];
    unsigned hs = h_task[task * 64 + lane];
    acc += __uint_as_float(hs << 16);
  }
  out[l * 64 + lane] = (c > 0) ? acc / (float)c : 0.f;
}

extern "C" void kernel_launch(void* const* d_in, const int* in_sizes, int n_in,
                              void* d_out, int out_size, void* d_ws, size_t ws_size,
                              hipStream_t stream) {
  const float* feat_ret  = (const float*)d_in[0];
  const float* feat_dram = (const float*)d_in[1];
  const float* feat_link = (const float*)d_in[2];
  const float* W_ret  = (const float*)d_in[3];
  const float* b_ret  = (const float*)d_in[4];
  const float* W_dram = (const float*)d_in[5];
  const float* b_dram = (const float*)d_in[6];
  const float* W_link = (const float*)d_in[7];
  const float* b_link = (const float*)d_in[8];
  const float* W_task = (const float*)d_in[9];
  const float* b_task = (const float*)d_in[10];
  const int* task_ret  = (const int*)d_in[11];
  const int* mod_ret   = (const int*)d_in[12];
  const int* task_dram = (const int*)d_in[13];
  const int* mod_dram  = (const int*)d_in[14];
  const int* task_link = (const int*)d_in[15];
  const int* mod_link  = (const int*)d_in[16];
  float* out = (float*)d_out;

  // ---- workspace layout (bytes) ----
  char* ws = (char*)d_ws;
  float*    s_ret  = (float*)(ws + 0);            // 20000 f
  float*    s_dram = (float*)(ws + 80000);        // 5000 f
  float*    s_link = (float*)(ws + 100000);       // 100000 f
  int*      cnt    = (int*)(ws + 500000);         // 100000 i
  unsigned* tmax   = (unsigned*)(ws + 900000);    // 150000 u
  // zero region: [0, 1500000)
  unsigned* tmin   = (unsigned*)(ws + 1500000);   // 150000 u, memset 0xFF
  int*      offs   = (int*)(ws + 2100000);        // 100000 i
  int*      cursor = (int*)(ws + 2500000);        // 100000 i
  int*      part   = (int*)(ws + 2900000);        // <=512 i
  int*      partx  = (int*)(ws + 2904096);        // <=512 i
  int*      csr    = (int*)(ws + 2908192);        // 2000000 i
  unsigned short* h_task = (unsigned short*)(ws + 10908192);  // 3200000 us

  hipMemsetAsync(ws, 0, 1500000, stream);
  hipMemsetAsync(ws + 1500000, 0xFF, 600000, stream);

  const int totalE = E_RET + E_DRAM + E_LINK;
  int nblk_e = (totalE + 255) / 256;
  k_segsum<<<nblk_e, 256, 0, stream>>>(feat_ret, feat_dram, feat_link,
                                       mod_ret, mod_dram, mod_link,
                                       s_ret, s_dram, s_link, cnt);
  k_minmax<<<nblk_e, 256, 0, stream>>>(s_ret, s_dram, s_link,
                                       task_ret, mod_ret, task_dram, mod_dram,
                                       task_link, mod_link, tmax, tmin);
  const int npart = (N_LINK + 255) / 256;  // 391
  k_part<<<npart, 256, 0, stream>>>(cnt, part);
  k_scanpart<<<1, 512, 0, stream>>>(part, partx, npart);
  k_offs<<<npart, 256, 0, stream>>>(cnt, partx, offs, cursor);
  k_scatter<<<(E_LINK + 255) / 256, 256, 0, stream>>>(task_link, mod_link, cursor, csr);
  k_task<<<(N_TASK + 63) / 64, 64, 0, stream>>>(W_ret, b_ret, W_dram, b_dram,
                                                W_link, b_link, W_task, b_task,
                                                tmax, tmin, h_task);
  k_link<<<N_LINK / 4, 256, 0, stream>>>(h_task, offs, cnt, csr, out);
}